// Round 17
// baseline (1249.865 us; speedup 1.0000x reference)
//
#include <hip/hip_runtime.h>
#include <stdint.h>

#define H 1536
#define SQ 2048
#define BB 4
#define MT 8192            // B*S tokens
#define NHD 12
#define INNER 6144
#define EPSF 1e-6f

typedef unsigned short u16;
typedef __bf16 b16x8 __attribute__((ext_vector_type(8)));
typedef float f32x4 __attribute__((ext_vector_type(4)));

__device__ __forceinline__ u16 f2b(float f) {
  uint32_t u = __float_as_uint(f);
  u = u + 0x7fffu + ((u >> 16) & 1u);
  return (u16)(u >> 16);
}
__device__ __forceinline__ float b2f(u16 u) { return __uint_as_float(((uint32_t)u) << 16); }
__device__ __forceinline__ float sigm(float x) { return 1.0f / (1.0f + __expf(-x)); }
// gelu with A&S 7.1.26 erf (|eps| <= 1.5e-7): ~15 VALU ops, no libm call
__device__ __forceinline__ float gelu_exact(float x) {
  float z = fabsf(x) * 0.70710678118654752f;
  float t = 1.0f / (1.0f + 0.3275911f * z);
  float p = t * (0.254829592f + t * (-0.284496736f + t * (1.421413741f +
            t * (-1.453152027f + t * 1.061405429f))));
  float erfa = 1.0f - p * __expf(-z * z);
  float erfv = (x >= 0.f) ? erfa : -erfa;
  return 0.5f * x * (1.0f + erfv);
}
__device__ __forceinline__ void load_lds16(const void* g, void* l) {
  __builtin_amdgcn_global_load_lds(
      (__attribute__((address_space(1))) void*)(g),
      (__attribute__((address_space(3))) void*)(l), 16, 0, 0);
}

// ---------------- RMSNorm: xhat -> bf16 (no norm_w; folded into weights) ----------------
__global__ __launch_bounds__(256) void k_rmsnorm(const float* __restrict__ x, u16* __restrict__ xb) {
  int m = blockIdx.x, t = threadIdx.x;
  const float* row = x + (size_t)m * H;
  float v[6]; float ss = 0.f;
#pragma unroll
  for (int j = 0; j < 6; ++j) { v[j] = row[t + j * 256]; ss += v[j] * v[j]; }
#pragma unroll
  for (int o = 32; o > 0; o >>= 1) ss += __shfl_xor(ss, o);
  __shared__ float red[4];
  if ((t & 63) == 0) red[t >> 6] = ss;
  __syncthreads();
  float r = rsqrtf((red[0] + red[1] + red[2] + red[3]) / (float)H + EPSF);
#pragma unroll
  for (int j = 0; j < 6; ++j) xb[(size_t)m * H + t + j * 256] = f2b(v[j] * r);
}

// -------- path gates (3) + router (12): 15 dots, 2 tokens/block interleaved --------
__global__ __launch_bounds__(256) void k_gates(const u16* __restrict__ xb, const float* __restrict__ norm_w,
    const float* __restrict__ pg_w, const float* __restrict__ pg_b,
    const float* __restrict__ router_w, const float* __restrict__ router_b,
    float* __restrict__ gates, float* __restrict__ hw) {
  int m0 = blockIdx.x * 2, t = threadIdx.x;
  const u16* row0 = xb + (size_t)m0 * H;
  const u16* row1 = row0 + H;
  float a0[15], a1[15];
#pragma unroll
  for (int i = 0; i < 15; ++i) { a0[i] = 0.f; a1[i] = 0.f; }
  for (int j = 0; j < 6; ++j) {
    int c = t + j * 256;
    float x0 = b2f(row0[c]), x1 = b2f(row1[c]);
    float n0 = norm_w[c], n1 = norm_w[H + c], n2 = norm_w[2 * H + c];
    float w0 = n0 * pg_w[c], w1 = n1 * pg_w[H + c], w2 = n2 * pg_w[2 * H + c];
    a0[0] += x0 * w0; a1[0] += x1 * w0;
    a0[1] += x0 * w1; a1[1] += x1 * w1;
    a0[2] += x0 * w2; a1[2] += x1 * w2;
    float xn0 = x0 * n1, xn1 = x1 * n1;
#pragma unroll
    for (int i = 0; i < 12; ++i) {
      float rw = router_w[(size_t)i * H + c];
      a0[3 + i] += xn0 * rw; a1[3 + i] += xn1 * rw;
    }
  }
  __shared__ float red[30][4];
#pragma unroll
  for (int i = 0; i < 15; ++i) {
    float s0 = a0[i], s1 = a1[i];
#pragma unroll
    for (int o = 32; o > 0; o >>= 1) { s0 += __shfl_xor(s0, o); s1 += __shfl_xor(s1, o); }
    if ((t & 63) == 0) { red[i][t >> 6] = s0; red[15 + i][t >> 6] = s1; }
  }
  __syncthreads();
  if (t < 30) {
    int tok = t / 15, i = t % 15;
    int m = m0 + tok;
    float s = red[t][0] + red[t][1] + red[t][2] + red[t][3];
    if (i < 3) gates[i * MT + m] = sigm(s + pg_b[i]);
    else hw[(size_t)m * NHD + (i - 3)] = sigm(s + router_b[i - 3]);
  }
}

// -------- weight -> bf16 (optional per-column scale = norm_w fold) --------
__global__ __launch_bounds__(256) void k_wcvt(const float* __restrict__ w, u16* __restrict__ wb,
                                              const float* __restrict__ cs, int K) {
  int c = blockIdx.x * 256 + threadIdx.x;
  size_t r = blockIdx.y;
  float v = w[r * K + c];
  if (cs) v *= cs[c];
  wb[r * K + c] = f2b(v);
}
// rows interleaved for fused GLU: dst row rr <- src row (rr&1 ? HALF+(rr>>1) : rr>>1)
__global__ __launch_bounds__(256) void k_wcvt2(const float* __restrict__ w, u16* __restrict__ wb,
                                               const float* __restrict__ cs, int K, int HALF) {
  int c = blockIdx.x * 256 + threadIdx.x;
  int rr = blockIdx.y;
  int src = (rr & 1) ? (HALF + (rr >> 1)) : (rr >> 1);
  wb[(size_t)rr * K + c] = f2b(w[(size_t)src * K + c] * cs[c]);
}

// -------- dilated conv stack step (bf16): 4 channels/thread (uint2), 8 s-positions --------
__global__ __launch_bounds__(384) void k_conv(const u16* __restrict__ in, u16* __restrict__ out,
    const float* __restrict__ w, const float* __restrict__ bias, int d, const float* __restrict__ insc) {
  int c = threadIdx.x * 4;                       // grid.x == 1, 384 threads * 4 = 1536 = H
  int s0 = blockIdx.y * 8, b = blockIdx.z;
  float sc[4];
#pragma unroll
  for (int q = 0; q < 4; ++q) sc[q] = insc ? insc[c + q] : 1.f;
  const u16* base = in + (size_t)b * SQ * H + c;
  u16* obase = out + (size_t)b * SQ * H + c;
  float4 wv[4];
#pragma unroll
  for (int q = 0; q < 4; ++q) wv[q] = *(const float4*)(w + (size_t)(c + q) * 4);
  float bv[4];
#pragma unroll
  for (int q = 0; q < 4; ++q) bv[q] = bias[c + q];
#pragma unroll
  for (int k = 0; k < 8; ++k) {
    int s = s0 + k;
    uint2 p = *(const uint2*)(base + (size_t)s * H);
    float cv[4] = { b2f((u16)p.x) * sc[0], b2f((u16)(p.x >> 16)) * sc[1],
                    b2f((u16)p.y) * sc[2], b2f((u16)(p.y >> 16)) * sc[3] };
    float a[4];
#pragma unroll
    for (int q = 0; q < 4; ++q) a[q] = bv[q] + wv[q].w * cv[q];
    if (s - d >= 0) {
      uint2 t2 = *(const uint2*)(base + (size_t)(s - d) * H);
      float tv[4] = { b2f((u16)t2.x) * sc[0], b2f((u16)(t2.x >> 16)) * sc[1],
                      b2f((u16)t2.y) * sc[2], b2f((u16)(t2.y >> 16)) * sc[3] };
#pragma unroll
      for (int q = 0; q < 4; ++q) a[q] += wv[q].z * tv[q];
    }
    if (s - 2 * d >= 0) {
      uint2 t2 = *(const uint2*)(base + (size_t)(s - 2 * d) * H);
      float tv[4] = { b2f((u16)t2.x) * sc[0], b2f((u16)(t2.x >> 16)) * sc[1],
                      b2f((u16)t2.y) * sc[2], b2f((u16)(t2.y >> 16)) * sc[3] };
#pragma unroll
      for (int q = 0; q < 4; ++q) a[q] += wv[q].y * tv[q];
    }
    if (s - 3 * d >= 0) {
      uint2 t2 = *(const uint2*)(base + (size_t)(s - 3 * d) * H);
      float tv[4] = { b2f((u16)t2.x) * sc[0], b2f((u16)(t2.x >> 16)) * sc[1],
                      b2f((u16)t2.y) * sc[2], b2f((u16)(t2.y >> 16)) * sc[3] };
#pragma unroll
      for (int q = 0; q < 4; ++q) a[q] += wv[q].x * tv[q];
    }
    uint2 r;
    r.x = ((uint32_t)f2b(cv[1] + gelu_exact(a[1])) << 16) | f2b(cv[0] + gelu_exact(a[0]));
    r.y = ((uint32_t)f2b(cv[3] + gelu_exact(a[3])) << 16) | f2b(cv[2] + gelu_exact(a[2]));
    *(uint2*)(obase + (size_t)s * H) = r;
  }
}

// -------- per-head dilated conv step (bf16): 4 channels/thread, 8 s-positions, head-weight fuse --------
__constant__ int HDILS[36] = {1,2,4, 1,1,1, 4,8,16, 8,16,32, 32,64,128, 64,128,256,
                              256,512,1024, 1,100,200, 1,500,1000, 1,1024,2048, 3,9,27, 5,25,125};

__global__ __launch_bounds__(384) void k_hconv(const u16* __restrict__ in, u16* __restrict__ out,
    const float* __restrict__ hws, const float* __restrict__ hbs, int j, const float* __restrict__ hwp) {
  int c = threadIdx.x * 4;                       // 4 | 128 => no head straddle
  int s0 = blockIdx.y * 8, b = blockIdx.z;
  int head = c >> 7, cc = c & 127;
  int d = HDILS[head * 3 + j];
  size_t wi = (size_t)(head * 3 + j) * 128 + cc;
  float4 wv[4];
#pragma unroll
  for (int q = 0; q < 4; ++q) wv[q] = *(const float4*)(hws + (wi + q) * 4);
  float bv[4];
#pragma unroll
  for (int q = 0; q < 4; ++q) bv[q] = hbs[wi + q];
  const u16* base = in + (size_t)b * SQ * H + c;
  u16* obase = out + (size_t)b * SQ * H + c;
#pragma unroll
  for (int k = 0; k < 8; ++k) {
    int s = s0 + k;
    uint2 p = *(const uint2*)(base + (size_t)s * H);
    float cv[4] = { b2f((u16)p.x), b2f((u16)(p.x >> 16)),
                    b2f((u16)p.y), b2f((u16)(p.y >> 16)) };
    float a[4];
#pragma unroll
    for (int q = 0; q < 4; ++q) a[q] = bv[q] + wv[q].w * cv[q];
    if (s - d >= 0) {
      uint2 t2 = *(const uint2*)(base + (size_t)(s - d) * H);
      float tv[4] = { b2f((u16)t2.x), b2f((u16)(t2.x >> 16)), b2f((u16)t2.y), b2f((u16)(t2.y >> 16)) };
#pragma unroll
      for (int q = 0; q < 4; ++q) a[q] += wv[q].z * tv[q];
    }
    if (s - 2 * d >= 0) {
      uint2 t2 = *(const uint2*)(base + (size_t)(s - 2 * d) * H);
      float tv[4] = { b2f((u16)t2.x), b2f((u16)(t2.x >> 16)), b2f((u16)t2.y), b2f((u16)(t2.y >> 16)) };
#pragma unroll
      for (int q = 0; q < 4; ++q) a[q] += wv[q].y * tv[q];
    }
    if (s - 3 * d >= 0) {
      uint2 t2 = *(const uint2*)(base + (size_t)(s - 3 * d) * H);
      float tv[4] = { b2f((u16)t2.x), b2f((u16)(t2.x >> 16)), b2f((u16)t2.y), b2f((u16)(t2.y >> 16)) };
#pragma unroll
      for (int q = 0; q < 4; ++q) a[q] += wv[q].x * tv[q];
    }
    float v[4];
#pragma unroll
    for (int q = 0; q < 4; ++q) v[q] = cv[q] + a[q];
    if (hwp) {
      float hv = hwp[((size_t)b * SQ + s) * NHD + head];
#pragma unroll
      for (int q = 0; q < 4; ++q) v[q] *= hv;
    }
    uint2 r;
    r.x = ((uint32_t)f2b(v[1]) << 16) | f2b(v[0]);
    r.y = ((uint32_t)f2b(v[3]) << 16) | f2b(v[2]);
    *(uint2*)(obase + (size_t)s * H) = r;
  }
}

// ======== 256x256 bf16 MFMA GEMM, BK=64, 8 waves — R6 proven structure ========
#define MMQ(AF, BF, MO, NO)                                                      \
  _Pragma("unroll") for (int m_ = 0; m_ < 4; ++m_)                               \
  _Pragma("unroll") for (int n_ = 0; n_ < 2; ++n_)                               \
  _Pragma("unroll") for (int ks_ = 0; ks_ < 2; ++ks_)                            \
    acc[(MO) + m_][(NO) + n_] = __builtin_amdgcn_mfma_f32_16x16x32_bf16(         \
        AF[m_][ks_], BF[n_][ks_], acc[(MO) + m_][(NO) + n_], 0, 0, 0);

#define TILE(BUF, SKO, DOSTAGE, VMSTMT)                                          \
  {                                                                              \
    b16x8 alo[4][2], ahi[4][2], blo[2][2], bhi[2][2];                            \
    _Pragma("unroll") for (int m = 0; m < 4; ++m) {                              \
      alo[m][0] = *(const b16x8*)(Ard0 + (BUF) * 16384 + m * 1024);              \
      alo[m][1] = *(const b16x8*)(Ard1 + (BUF) * 16384 + m * 1024);              \
    }                                                                            \
    _Pragma("unroll") for (int n = 0; n < 2; ++n) {                              \
      blo[n][0] = *(const b16x8*)(Brd0 + (BUF) * 16384 + n * 1024);              \
      blo[n][1] = *(const b16x8*)(Brd1 + (BUF) * 16384 + n * 1024);              \
    }                                                                            \
    asm volatile("s_waitcnt lgkmcnt(8)" ::: "memory");                           \
    __builtin_amdgcn_sched_barrier(0);                                           \
    __builtin_amdgcn_s_barrier();                                                \
    asm volatile("s_waitcnt lgkmcnt(0)" ::: "memory");                           \
    __builtin_amdgcn_sched_barrier(0);                                           \
    __builtin_amdgcn_s_setprio(1);                                               \
    MMQ(alo, blo, 0, 0);                                                         \
    __builtin_amdgcn_s_setprio(0);                                               \
    __builtin_amdgcn_sched_barrier(0);                                           \
    __builtin_amdgcn_s_barrier();                                                \
    _Pragma("unroll") for (int n = 0; n < 2; ++n) {                              \
      bhi[n][0] = *(const b16x8*)(Brd0 + (BUF) * 16384 + 2048 + n * 1024);       \
      bhi[n][1] = *(const b16x8*)(Brd1 + (BUF) * 16384 + 2048 + n * 1024);       \
    }                                                                            \
    __builtin_amdgcn_sched_barrier(0);                                           \
    __builtin_amdgcn_s_barrier();                                                \
    asm volatile("s_waitcnt lgkmcnt(0)" ::: "memory");                           \
    __builtin_amdgcn_sched_barrier(0);                                           \
    __builtin_amdgcn_s_setprio(1);                                               \
    MMQ(alo, bhi, 0, 2);                                                         \
    __builtin_amdgcn_s_setprio(0);                                               \
    __builtin_amdgcn_sched_barrier(0);                                           \
    __builtin_amdgcn_s_barrier();                                                \
    _Pragma("unroll") for (int m = 0; m < 4; ++m) {                              \
      ahi[m][0] = *(const b16x8*)(Ard0 + (BUF) * 16384 + 4096 + m * 1024);       \
      ahi[m][1] = *(const b16x8*)(Ard1 + (BUF) * 16384 + 4096 + m * 1024);       \
    }                                                                            \
    if (DOSTAGE) {                                                               \
      load_lds16(Bgp + (boff0 + (SKO)), dB0 + (BUF) * 16384);                    \
      load_lds16(Bgp + (boff1 + (SKO)), dB1 + (BUF) * 16384);                    \
      load_lds16(Bgp + (boff2 + (SKO)), dB2 + (BUF) * 16384);                    \
      load_lds16(Bgp + (boff3 + (SKO)), dB3 + (BUF) * 16384);                    \
    }                                                                            \
    __builtin_amdgcn_sched_barrier(0);                                           \
    __builtin_amdgcn_s_barrier();                                                \
    asm volatile("s_waitcnt lgkmcnt(0)" ::: "memory");                           \
    __builtin_amdgcn_sched_barrier(0);                                           \
    __builtin_amdgcn_s_setprio(1);                                               \
    MMQ(ahi, bhi, 4, 2);                                                         \
    __builtin_amdgcn_s_setprio(0);                                               \
    __builtin_amdgcn_sched_barrier(0);                                           \
    __builtin_amdgcn_s_barrier();                                                \
    if (DOSTAGE) {                                                               \
      load_lds16(Agp + (aoff0 + (SKO)), dA0 + (BUF) * 16384);                    \
      load_lds16(Agp + (aoff1 + (SKO)), dA1 + (BUF) * 16384);                    \
      load_lds16(Agp + (aoff2 + (SKO)), dA2 + (BUF) * 16384);                    \
      load_lds16(Agp + (aoff3 + (SKO)), dA3 + (BUF) * 16384);                    \
    }                                                                            \
    __builtin_amdgcn_sched_barrier(0);                                           \
    __builtin_amdgcn_s_barrier();                                                \
    __builtin_amdgcn_s_setprio(1);                                               \
    MMQ(ahi, blo, 4, 0);                                                         \
    __builtin_amdgcn_s_setprio(0);                                               \
    VMSTMT;                                                                      \
    __builtin_amdgcn_sched_barrier(0);                                           \
    __builtin_amdgcn_s_barrier();                                                \
  }

// MODE 0: Cf32[r,col]  = xres[r,col] + (acc+bias[col]) * gate[r]
// MODE 1: Cf32[r,col] += (acc+bias?[col]) * gate?[r]
// MODE 2: fused GLU -> bf16: even col lanes write f2b(a*sigm(b)) at [r*ldc + (col>>1)]
// MODE 3: Cb16[r,col] = f2b(aux[r,col] * sigm(acc+bias[col]))
template<int MODE>
__global__ __launch_bounds__(512, 1) void k_gemm(const u16* __restrict__ A, int lda,
    const u16* __restrict__ B, int ldb, void* __restrict__ Cout, int M, int N, int K,
    const float* __restrict__ bias, const float* __restrict__ gate, const u16* __restrict__ aux,
    const float* __restrict__ xres, int ldc) {
  __shared__ u16 lds[65536];                           // 128 KiB
  int tid = threadIdx.x;
  int w = tid >> 6, lane = tid & 63;
  int l15 = lane & 15, l4 = lane >> 4;
  int wr = w >> 2, wc = w & 3;

  // XCD-aware bijective swizzle, bm-fastest within each XCD's bm band.
  int gx = gridDim.x, gy = gridDim.y;
  int nwg = gx * gy;
  int bid = blockIdx.y * gx + blockIdx.x;
  int bm, bn;
  if (((nwg & 7) == 0) && ((gy & 7) == 0)) {
    int xcd = bid & 7, l = bid >> 3;
    int rpx = gy >> 3;
    bm = xcd * rpx + (l % rpx);
    bn = l / rpx;
  } else { bn = bid % gx; bm = bid / gx; }

  const u16* Agp = A + (size_t)bm * 256 * lda;
  const u16* Bgp = B + (size_t)bn * 256 * ldb;
  int nt = K >> 6;

  f32x4 acc[8][4];
#pragma unroll
  for (int m = 0; m < 8; ++m)
#pragma unroll
    for (int n = 0; n < 4; ++n) acc[m][n] = f32x4{0.f, 0.f, 0.f, 0.f};

  int m7 = l15 & 7;
  int slot0 = l4 ^ m7, slot1 = slot0 ^ 4;
  const u16* Ard0 = lds + wr * 8192 + l15 * 64 + slot0 * 8;
  const u16* Ard1 = lds + wr * 8192 + l15 * 64 + slot1 * 8;
  const u16* Brd0 = lds + 32768 + (wc >> 1) * 8192 + ((wc & 1) * 64 + l15) * 64 + slot0 * 8;
  const u16* Brd1 = lds + 32768 + (wc >> 1) * 8192 + ((wc & 1) * 64 + l15) * 64 + slot1 * 8;

  int r0 = tid >> 3;
  int kg = ((lane & 7) ^ (lane >> 3)) * 8;
  int aoff0 = (0 * 128 + 0 * 64 + r0) * lda + kg;
  int aoff1 = (0 * 128 + 1 * 64 + r0) * lda + kg;
  int aoff2 = (1 * 128 + 0 * 64 + r0) * lda + kg;
  int aoff3 = (1 * 128 + 1 * 64 + r0) * lda + kg;
  int boff0 = (0 * 128 + 0 * 64 + r0) * ldb + kg;
  int boff1 = (0 * 128 + 1 * 64 + r0) * ldb + kg;
  int boff2 = (1 * 128 + 0 * 64 + r0) * ldb + kg;
  int boff3 = (1 * 128 + 1 * 64 + r0) * ldb + kg;
  int w512 = w * 512;
  u16* dA0 = lds + 0 * 4096 + w512;
  u16* dA1 = lds + 1 * 4096 + w512;
  u16* dA2 = lds + 2 * 4096 + w512;
  u16* dA3 = lds + 3 * 4096 + w512;
  u16* dB0 = lds + 32768 + 0 * 4096 + w512;
  u16* dB1 = lds + 32768 + 1 * 4096 + w512;
  u16* dB2 = lds + 32768 + 2 * 4096 + w512;
  u16* dB3 = lds + 32768 + 3 * 4096 + w512;

  load_lds16(Bgp + boff0, dB0); load_lds16(Bgp + boff1, dB1);
  load_lds16(Bgp + boff2, dB2); load_lds16(Bgp + boff3, dB3);
  load_lds16(Agp + aoff0, dA0); load_lds16(Agp + aoff1, dA1);
  load_lds16(Agp + aoff2, dA2); load_lds16(Agp + aoff3, dA3);
  load_lds16(Bgp + boff0 + 64, dB0 + 16384); load_lds16(Bgp + boff1 + 64, dB1 + 16384);
  load_lds16(Bgp + boff2 + 64, dB2 + 16384); load_lds16(Bgp + boff3 + 64, dB3 + 16384);
  load_lds16(Agp + aoff0 + 64, dA0 + 16384); load_lds16(Agp + aoff1 + 64, dA1 + 16384);
  load_lds16(Agp + aoff2 + 64, dA2 + 16384); load_lds16(Agp + aoff3 + 64, dA3 + 16384);
  asm volatile("s_waitcnt vmcnt(8)" ::: "memory");
  __builtin_amdgcn_s_barrier();
  __builtin_amdgcn_sched_barrier(0);

  int koff = 0;
  int main_iters = (nt >> 1) - 1;
  for (int it = 0; it < main_iters; ++it) {
    TILE(0, koff + 128, true, asm volatile("s_waitcnt vmcnt(8)" ::: "memory"));
    TILE(1, koff + 192, true, asm volatile("s_waitcnt vmcnt(8)" ::: "memory"));
    koff += 128;
  }
  TILE(0, 0, false, asm volatile("s_waitcnt vmcnt(0)" ::: "memory"));
  TILE(1, 0, false, (void)0);

  int rowbase = bm * 256 + wr * 128;
  int colbase = bn * 256 + wc * 64;
#pragma unroll
  for (int n = 0; n < 4; ++n) {
    int col = colbase + n * 16 + l15;
    float bv = (MODE == 2) ? 0.f : (bias ? bias[col] : 0.f);
#pragma unroll
    for (int m = 0; m < 8; ++m) {
#pragma unroll
      for (int j = 0; j < 4; ++j) {
        int r = rowbase + m * 16 + l4 * 4 + j;
        float val = acc[m][n][j];
        if (MODE == 0) {
          size_t idx = (size_t)r * N + col;
          ((float*)Cout)[idx] = xres[idx] + (val + bv) * gate[r];
        } else if (MODE == 1) {
          ((float*)Cout)[(size_t)r * N + col] += (val + bv) * (gate ? gate[r] : 1.f);
        } else if (MODE == 2) {
          float other = __shfl_xor(val, 1);
          if ((lane & 1) == 0)
            ((u16*)Cout)[(size_t)r * ldc + (col >> 1)] = f2b(val * sigm(other));
        } else {
          float a = b2f(aux[(size_t)r * N + col]);
          ((u16*)Cout)[(size_t)r * N + col] = f2b(a * sigm(val + bv));
        }
      }
    }
  }
}

extern "C" void kernel_launch(void* const* d_in, const int* in_sizes, int n_in,
                              void* d_out, int out_size, void* d_ws, size_t ws_size,
                              hipStream_t stream) {
  const float* x        = (const float*)d_in[0];
  const float* norm_w   = (const float*)d_in[1];
  const float* conv_ws  = (const float*)d_in[2];
  const float* conv_bs  = (const float*)d_in[3];
  const float* conv_pw  = (const float*)d_in[4];
  const float* conv_pb  = (const float*)d_in[5];
  const float* gate_w   = (const float*)d_in[6];
  const float* router_w = (const float*)d_in[7];
  const float* router_b = (const float*)d_in[8];
  const float* head_ws  = (const float*)d_in[9];
  const float* head_bs  = (const float*)d_in[10];
  const float* mixg_w   = (const float*)d_in[11];
  const float* mixg_b   = (const float*)d_in[12];
  const float* mix_w    = (const float*)d_in[13];
  const float* mix_b    = (const float*)d_in[14];
  const float* ffn_iw   = (const float*)d_in[15];
  const float* ffn_ow   = (const float*)d_in[16];
  const float* pg_w     = (const float*)d_in[17];
  const float* pg_b     = (const float*)d_in[18];
  float* out = (float*)d_out;

  char* ws = (char*)d_ws;
  size_t o = 0;
  auto alloc = [&](size_t n) { char* p = ws + o; o += n; return p; };
  u16*  XB  = (u16*)alloc(25165824);    // xhat bf16 [8192,1536]
  u16*  A16 = (u16*)alloc(25165824);    // bf16 ping
  u16*  B16 = (u16*)alloc(25165824);    // bf16 pong
  u16*  WG2 = (u16*)alloc(9437184);     // gate_w interleaved * nw1 [3072,1536]
  u16*  WP  = (u16*)alloc(4718592);     // conv_proj [1536,1536]
  u16*  WMG = (u16*)alloc(4718592);     // mix_gate [1536,1536]
  u16*  WMX = (u16*)alloc(4718592);     // mixing [1536,1536]
  u16*  WFI = (u16*)alloc(37748736);    // ffn_in interleaved * nw2 [12288,1536]
  u16*  WFO = (u16*)alloc(18874368);    // ffn_out [1536,6144]
  float* gates = (float*)alloc(98304);  // [3][8192]
  float* hw    = (float*)alloc(393216); // [8192][12]
  u16*  VB = A16;                       // fallback FFN V chunk [8192,3072] (aliases A16+B16)
  size_t base_end = o;
  bool bigws = (ws_size >= base_end + 100663296ull);   // full V [8192,6144] bf16 (proven fit, R10)
  u16* VX = bigws ? (u16*)alloc(100663296) : nullptr;

  k_rmsnorm<<<MT, 256, 0, stream>>>(x, XB);
  k_gates<<<MT / 2, 256, 0, stream>>>(XB, norm_w, pg_w, pg_b, router_w, router_b, gates, hw);

  k_wcvt2<<<dim3(6, 3072),  256, 0, stream>>>(gate_w, WG2, norm_w + H, H, H);
  k_wcvt <<<dim3(6, 1536),  256, 0, stream>>>(conv_pw, WP, nullptr, H);
  k_wcvt <<<dim3(6, 1536),  256, 0, stream>>>(mixg_w, WMG, nullptr, H);
  k_wcvt <<<dim3(6, 1536),  256, 0, stream>>>(mix_w, WMX, nullptr, H);
  k_wcvt2<<<dim3(6, 12288), 256, 0, stream>>>(ffn_iw, WFI, norm_w + 2 * H, H, INNER);
  k_wcvt <<<dim3(24, 1536), 256, 0, stream>>>(ffn_ow, WFO, nullptr, INNER);

  // ---- conv stack path: 6 blocked steps, 4 channels/thread (norm_w0 folded on step 0) ----
  dim3 cg(1, SQ / 8, BB);
  k_conv<<<cg, 384, 0, stream>>>(XB,  A16, conv_ws + 0 * H * 4, conv_bs + 0 * H, 1,  norm_w);
  k_conv<<<cg, 384, 0, stream>>>(A16, B16, conv_ws + 1 * H * 4, conv_bs + 1 * H, 2,  nullptr);
  k_conv<<<cg, 384, 0, stream>>>(B16, A16, conv_ws + 2 * H * 4, conv_bs + 2 * H, 4,  nullptr);
  k_conv<<<cg, 384, 0, stream>>>(A16, B16, conv_ws + 3 * H * 4, conv_bs + 3 * H, 8,  nullptr);
  k_conv<<<cg, 384, 0, stream>>>(B16, A16, conv_ws + 4 * H * 4, conv_bs + 4 * H, 16, nullptr);
  k_conv<<<cg, 384, 0, stream>>>(A16, B16, conv_ws + 5 * H * 4, conv_bs + 5 * H, 32, nullptr);
  // conv_out proj, gated by gc, + residual x fused -> out
  k_gemm<0><<<dim3(6, 32), 512, 0, stream>>>(B16, H, WP, H, out, MT, H, H, conv_pb, gates, nullptr, x, 0);

  // ---- state path ----
  // gate GEMM + fused GLU -> x_gated bf16 in A16 (ldc = H)
  k_gemm<2><<<dim3(12, 32), 512, 0, stream>>>(XB, H, WG2, H, A16, MT, 2 * H, H, nullptr, nullptr, nullptr, nullptr, H);
  k_hconv<<<cg, 384, 0, stream>>>(A16, B16, head_ws, head_bs, 0, nullptr);
  k_hconv<<<cg, 384, 0, stream>>>(B16, A16, head_ws, head_bs, 1, nullptr);
  k_hconv<<<cg, 384, 0, stream>>>(A16, B16, head_ws, head_bs, 2, hw);   // j2 + head-weight fused
  // mix_gate GEMM + fused out2: A16 = f2b(B16 * sigm(mg))
  k_gemm<3><<<dim3(6, 32), 512, 0, stream>>>(B16, H, WMG, H, A16, MT, H, H, mixg_b, nullptr, B16, nullptr, 0);
  // mixing GEMM, gated by gs, accumulates into out
  k_gemm<1><<<dim3(6, 32), 512, 0, stream>>>(A16, H, WMX, H, out, MT, H, H, mix_b, gates + MT, nullptr, nullptr, 0);

  // ---- GLU FFN path ----
  if (bigws) {
    // ffn_in chunks -> full-V halves (ldc=INNER); ONE K=6144 ffn_out (single RMW of out)
    for (int ch = 0; ch < 2; ++ch) {
      k_gemm<2><<<dim3(24, 32), 512, 0, stream>>>(XB, H, WFI + (size_t)ch * 6144 * H, H,
                                                  VX + ch * 3072, MT, 6144, H,
                                                  nullptr, nullptr, nullptr, nullptr, INNER);
    }
    k_gemm<1><<<dim3(6, 32), 512, 0, stream>>>(VX, INNER, WFO, INNER, out, MT, H, INNER,
                                               nullptr, gates + 2 * MT, nullptr, nullptr, 0);
  } else {
    for (int ch = 0; ch < 2; ++ch) {
      k_gemm<2><<<dim3(24, 32), 512, 0, stream>>>(XB, H, WFI + (size_t)ch * 6144 * H, H,
                                                  VB, MT, 6144, H, nullptr, nullptr, nullptr, nullptr, 3072);
      k_gemm<1><<<dim3(6, 32), 512, 0, stream>>>(VB, 3072, WFO + ch * 3072, INNER,
                                                 out, MT, H, 3072, nullptr, gates + 2 * MT, nullptr, nullptr, 0);
    }
  }
}

// Round 18
// 1205.888 us; speedup vs baseline: 1.0365x; 1.0365x over previous
//
#include <hip/hip_runtime.h>
#include <stdint.h>

#define H 1536
#define SQ 2048
#define BB 4
#define MT 8192            // B*S tokens
#define NHD 12
#define INNER 6144
#define EPSF 1e-6f

typedef unsigned short u16;
typedef __bf16 b16x8 __attribute__((ext_vector_type(8)));
typedef float f32x4 __attribute__((ext_vector_type(4)));

__device__ __forceinline__ u16 f2b(float f) {
  uint32_t u = __float_as_uint(f);
  u = u + 0x7fffu + ((u >> 16) & 1u);
  return (u16)(u >> 16);
}
__device__ __forceinline__ float b2f(u16 u) { return __uint_as_float(((uint32_t)u) << 16); }
__device__ __forceinline__ float sigm(float x) { return 1.0f / (1.0f + __expf(-x)); }
// gelu with A&S 7.1.26 erf (|eps| <= 1.5e-7): ~15 VALU ops, no libm call
__device__ __forceinline__ float gelu_exact(float x) {
  float z = fabsf(x) * 0.70710678118654752f;
  float t = 1.0f / (1.0f + 0.3275911f * z);
  float p = t * (0.254829592f + t * (-0.284496736f + t * (1.421413741f +
            t * (-1.453152027f + t * 1.061405429f))));
  float erfa = 1.0f - p * __expf(-z * z);
  float erfv = (x >= 0.f) ? erfa : -erfa;
  return 0.5f * x * (1.0f + erfv);
}
__device__ __forceinline__ void load_lds16(const void* g, void* l) {
  __builtin_amdgcn_global_load_lds(
      (__attribute__((address_space(1))) void*)(g),
      (__attribute__((address_space(3))) void*)(l), 16, 0, 0);
}

// ---------------- RMSNorm: xhat -> bf16 (no norm_w; folded into weights) ----------------
__global__ __launch_bounds__(256) void k_rmsnorm(const float* __restrict__ x, u16* __restrict__ xb) {
  int m = blockIdx.x, t = threadIdx.x;
  const float* row = x + (size_t)m * H;
  float v[6]; float ss = 0.f;
#pragma unroll
  for (int j = 0; j < 6; ++j) { v[j] = row[t + j * 256]; ss += v[j] * v[j]; }
#pragma unroll
  for (int o = 32; o > 0; o >>= 1) ss += __shfl_xor(ss, o);
  __shared__ float red[4];
  if ((t & 63) == 0) red[t >> 6] = ss;
  __syncthreads();
  float r = rsqrtf((red[0] + red[1] + red[2] + red[3]) / (float)H + EPSF);
#pragma unroll
  for (int j = 0; j < 6; ++j) xb[(size_t)m * H + t + j * 256] = f2b(v[j] * r);
}

// -------- path gates (3) + router (12): 15 dots per token --------
__global__ __launch_bounds__(256) void k_gates(const u16* __restrict__ xb, const float* __restrict__ norm_w,
    const float* __restrict__ pg_w, const float* __restrict__ pg_b,
    const float* __restrict__ router_w, const float* __restrict__ router_b,
    float* __restrict__ gates, float* __restrict__ hw) {
  int m = blockIdx.x, t = threadIdx.x;
  const u16* row = xb + (size_t)m * H;
  float acc[15];
#pragma unroll
  for (int i = 0; i < 15; ++i) acc[i] = 0.f;
  for (int j = 0; j < 6; ++j) {
    int c = t + j * 256;
    float xv = b2f(row[c]);
    float n0 = norm_w[c], n1 = norm_w[H + c], n2 = norm_w[2 * H + c];
    acc[0] += xv * n0 * pg_w[c];
    acc[1] += xv * n1 * pg_w[H + c];
    acc[2] += xv * n2 * pg_w[2 * H + c];
    float xn = xv * n1;
#pragma unroll
    for (int i = 0; i < 12; ++i) acc[3 + i] += xn * router_w[(size_t)i * H + c];
  }
  __shared__ float red[15][4];
#pragma unroll
  for (int i = 0; i < 15; ++i) {
    float s = acc[i];
#pragma unroll
    for (int o = 32; o > 0; o >>= 1) s += __shfl_xor(s, o);
    if ((t & 63) == 0) red[i][t >> 6] = s;
  }
  __syncthreads();
  if (t < 15) {
    float s = red[t][0] + red[t][1] + red[t][2] + red[t][3];
    if (t < 3) gates[t * MT + m] = sigm(s + pg_b[t]);
    else hw[(size_t)m * NHD + (t - 3)] = sigm(s + router_b[t - 3]);
  }
}

// -------- weight -> bf16 (optional per-column scale = norm_w fold) --------
__global__ __launch_bounds__(256) void k_wcvt(const float* __restrict__ w, u16* __restrict__ wb,
                                              const float* __restrict__ cs, int K) {
  int c = blockIdx.x * 256 + threadIdx.x;
  size_t r = blockIdx.y;
  float v = w[r * K + c];
  if (cs) v *= cs[c];
  wb[r * K + c] = f2b(v);
}
// rows interleaved for fused GLU: dst row rr <- src row (rr&1 ? HALF+(rr>>1) : rr>>1)
__global__ __launch_bounds__(256) void k_wcvt2(const float* __restrict__ w, u16* __restrict__ wb,
                                               const float* __restrict__ cs, int K, int HALF) {
  int c = blockIdx.x * 256 + threadIdx.x;
  int rr = blockIdx.y;
  int src = (rr & 1) ? (HALF + (rr >> 1)) : (rr >> 1);
  wb[(size_t)rr * K + c] = f2b(w[(size_t)src * K + c] * cs[c]);
}

// -------- dilated conv stack step (bf16): 4 channels/thread (uint2), 8 s-positions --------
__global__ __launch_bounds__(384) void k_conv(const u16* __restrict__ in, u16* __restrict__ out,
    const float* __restrict__ w, const float* __restrict__ bias, int d, const float* __restrict__ insc) {
  int c = threadIdx.x * 4;                       // grid.x == 1, 384 threads * 4 = 1536 = H
  int s0 = blockIdx.y * 8, b = blockIdx.z;
  float sc[4];
#pragma unroll
  for (int q = 0; q < 4; ++q) sc[q] = insc ? insc[c + q] : 1.f;
  const u16* base = in + (size_t)b * SQ * H + c;
  u16* obase = out + (size_t)b * SQ * H + c;
  float4 wv[4];
#pragma unroll
  for (int q = 0; q < 4; ++q) wv[q] = *(const float4*)(w + (size_t)(c + q) * 4);
  float bv[4];
#pragma unroll
  for (int q = 0; q < 4; ++q) bv[q] = bias[c + q];
#pragma unroll
  for (int k = 0; k < 8; ++k) {
    int s = s0 + k;
    uint2 p = *(const uint2*)(base + (size_t)s * H);
    float cv[4] = { b2f((u16)p.x) * sc[0], b2f((u16)(p.x >> 16)) * sc[1],
                    b2f((u16)p.y) * sc[2], b2f((u16)(p.y >> 16)) * sc[3] };
    float a[4];
#pragma unroll
    for (int q = 0; q < 4; ++q) a[q] = bv[q] + wv[q].w * cv[q];
    if (s - d >= 0) {
      uint2 t2 = *(const uint2*)(base + (size_t)(s - d) * H);
      float tv[4] = { b2f((u16)t2.x) * sc[0], b2f((u16)(t2.x >> 16)) * sc[1],
                      b2f((u16)t2.y) * sc[2], b2f((u16)(t2.y >> 16)) * sc[3] };
#pragma unroll
      for (int q = 0; q < 4; ++q) a[q] += wv[q].z * tv[q];
    }
    if (s - 2 * d >= 0) {
      uint2 t2 = *(const uint2*)(base + (size_t)(s - 2 * d) * H);
      float tv[4] = { b2f((u16)t2.x) * sc[0], b2f((u16)(t2.x >> 16)) * sc[1],
                      b2f((u16)t2.y) * sc[2], b2f((u16)(t2.y >> 16)) * sc[3] };
#pragma unroll
      for (int q = 0; q < 4; ++q) a[q] += wv[q].y * tv[q];
    }
    if (s - 3 * d >= 0) {
      uint2 t2 = *(const uint2*)(base + (size_t)(s - 3 * d) * H);
      float tv[4] = { b2f((u16)t2.x) * sc[0], b2f((u16)(t2.x >> 16)) * sc[1],
                      b2f((u16)t2.y) * sc[2], b2f((u16)(t2.y >> 16)) * sc[3] };
#pragma unroll
      for (int q = 0; q < 4; ++q) a[q] += wv[q].x * tv[q];
    }
    uint2 r;
    r.x = ((uint32_t)f2b(cv[1] + gelu_exact(a[1])) << 16) | f2b(cv[0] + gelu_exact(a[0]));
    r.y = ((uint32_t)f2b(cv[3] + gelu_exact(a[3])) << 16) | f2b(cv[2] + gelu_exact(a[2]));
    *(uint2*)(obase + (size_t)s * H) = r;
  }
}

// -------- per-head dilated conv step (bf16): 4 channels/thread, 8 s-positions, head-weight fuse --------
__constant__ int HDILS[36] = {1,2,4, 1,1,1, 4,8,16, 8,16,32, 32,64,128, 64,128,256,
                              256,512,1024, 1,100,200, 1,500,1000, 1,1024,2048, 3,9,27, 5,25,125};

__global__ __launch_bounds__(384) void k_hconv(const u16* __restrict__ in, u16* __restrict__ out,
    const float* __restrict__ hws, const float* __restrict__ hbs, int j, const float* __restrict__ hwp) {
  int c = threadIdx.x * 4;                       // 4 | 128 => no head straddle
  int s0 = blockIdx.y * 8, b = blockIdx.z;
  int head = c >> 7, cc = c & 127;
  int d = HDILS[head * 3 + j];
  size_t wi = (size_t)(head * 3 + j) * 128 + cc;
  float4 wv[4];
#pragma unroll
  for (int q = 0; q < 4; ++q) wv[q] = *(const float4*)(hws + (wi + q) * 4);
  float bv[4];
#pragma unroll
  for (int q = 0; q < 4; ++q) bv[q] = hbs[wi + q];
  const u16* base = in + (size_t)b * SQ * H + c;
  u16* obase = out + (size_t)b * SQ * H + c;
#pragma unroll
  for (int k = 0; k < 8; ++k) {
    int s = s0 + k;
    uint2 p = *(const uint2*)(base + (size_t)s * H);
    float cv[4] = { b2f((u16)p.x), b2f((u16)(p.x >> 16)),
                    b2f((u16)p.y), b2f((u16)(p.y >> 16)) };
    float a[4];
#pragma unroll
    for (int q = 0; q < 4; ++q) a[q] = bv[q] + wv[q].w * cv[q];
    if (s - d >= 0) {
      uint2 t2 = *(const uint2*)(base + (size_t)(s - d) * H);
      float tv[4] = { b2f((u16)t2.x), b2f((u16)(t2.x >> 16)), b2f((u16)t2.y), b2f((u16)(t2.y >> 16)) };
#pragma unroll
      for (int q = 0; q < 4; ++q) a[q] += wv[q].z * tv[q];
    }
    if (s - 2 * d >= 0) {
      uint2 t2 = *(const uint2*)(base + (size_t)(s - 2 * d) * H);
      float tv[4] = { b2f((u16)t2.x), b2f((u16)(t2.x >> 16)), b2f((u16)t2.y), b2f((u16)(t2.y >> 16)) };
#pragma unroll
      for (int q = 0; q < 4; ++q) a[q] += wv[q].y * tv[q];
    }
    if (s - 3 * d >= 0) {
      uint2 t2 = *(const uint2*)(base + (size_t)(s - 3 * d) * H);
      float tv[4] = { b2f((u16)t2.x), b2f((u16)(t2.x >> 16)), b2f((u16)t2.y), b2f((u16)(t2.y >> 16)) };
#pragma unroll
      for (int q = 0; q < 4; ++q) a[q] += wv[q].x * tv[q];
    }
    float v[4];
#pragma unroll
    for (int q = 0; q < 4; ++q) v[q] = cv[q] + a[q];
    if (hwp) {
      float hv = hwp[((size_t)b * SQ + s) * NHD + head];
#pragma unroll
      for (int q = 0; q < 4; ++q) v[q] *= hv;
    }
    uint2 r;
    r.x = ((uint32_t)f2b(v[1]) << 16) | f2b(v[0]);
    r.y = ((uint32_t)f2b(v[3]) << 16) | f2b(v[2]);
    *(uint2*)(obase + (size_t)s * H) = r;
  }
}

// ======== 256x256 bf16 MFMA GEMM, BK=64, 8 waves — R6 proven structure ========
#define MMQ(AF, BF, MO, NO)                                                      \
  _Pragma("unroll") for (int m_ = 0; m_ < 4; ++m_)                               \
  _Pragma("unroll") for (int n_ = 0; n_ < 2; ++n_)                               \
  _Pragma("unroll") for (int ks_ = 0; ks_ < 2; ++ks_)                            \
    acc[(MO) + m_][(NO) + n_] = __builtin_amdgcn_mfma_f32_16x16x32_bf16(         \
        AF[m_][ks_], BF[n_][ks_], acc[(MO) + m_][(NO) + n_], 0, 0, 0);

#define TILE(BUF, SKO, DOSTAGE, VMSTMT)                                          \
  {                                                                              \
    b16x8 alo[4][2], ahi[4][2], blo[2][2], bhi[2][2];                            \
    _Pragma("unroll") for (int m = 0; m < 4; ++m) {                              \
      alo[m][0] = *(const b16x8*)(Ard0 + (BUF) * 16384 + m * 1024);              \
      alo[m][1] = *(const b16x8*)(Ard1 + (BUF) * 16384 + m * 1024);              \
    }                                                                            \
    _Pragma("unroll") for (int n = 0; n < 2; ++n) {                              \
      blo[n][0] = *(const b16x8*)(Brd0 + (BUF) * 16384 + n * 1024);              \
      blo[n][1] = *(const b16x8*)(Brd1 + (BUF) * 16384 + n * 1024);              \
    }                                                                            \
    asm volatile("s_waitcnt lgkmcnt(8)" ::: "memory");                           \
    __builtin_amdgcn_sched_barrier(0);                                           \
    __builtin_amdgcn_s_barrier();                                                \
    asm volatile("s_waitcnt lgkmcnt(0)" ::: "memory");                           \
    __builtin_amdgcn_sched_barrier(0);                                           \
    __builtin_amdgcn_s_setprio(1);                                               \
    MMQ(alo, blo, 0, 0);                                                         \
    __builtin_amdgcn_s_setprio(0);                                               \
    __builtin_amdgcn_sched_barrier(0);                                           \
    __builtin_amdgcn_s_barrier();                                                \
    _Pragma("unroll") for (int n = 0; n < 2; ++n) {                              \
      bhi[n][0] = *(const b16x8*)(Brd0 + (BUF) * 16384 + 2048 + n * 1024);       \
      bhi[n][1] = *(const b16x8*)(Brd1 + (BUF) * 16384 + 2048 + n * 1024);       \
    }                                                                            \
    __builtin_amdgcn_sched_barrier(0);                                           \
    __builtin_amdgcn_s_barrier();                                                \
    asm volatile("s_waitcnt lgkmcnt(0)" ::: "memory");                           \
    __builtin_amdgcn_sched_barrier(0);                                           \
    __builtin_amdgcn_s_setprio(1);                                               \
    MMQ(alo, bhi, 0, 2);                                                         \
    __builtin_amdgcn_s_setprio(0);                                               \
    __builtin_amdgcn_sched_barrier(0);                                           \
    __builtin_amdgcn_s_barrier();                                                \
    _Pragma("unroll") for (int m = 0; m < 4; ++m) {                              \
      ahi[m][0] = *(const b16x8*)(Ard0 + (BUF) * 16384 + 4096 + m * 1024);       \
      ahi[m][1] = *(const b16x8*)(Ard1 + (BUF) * 16384 + 4096 + m * 1024);       \
    }                                                                            \
    if (DOSTAGE) {                                                               \
      load_lds16(Bg + (boff0 + (SKO)), dB0 + (BUF) * 16384);                     \
      load_lds16(Bg + (boff1 + (SKO)), dB1 + (BUF) * 16384);                     \
      load_lds16(Bg + (boff2 + (SKO)), dB2 + (BUF) * 16384);                     \
      load_lds16(Bg + (boff3 + (SKO)), dB3 + (BUF) * 16384);                     \
    }                                                                            \
    __builtin_amdgcn_sched_barrier(0);                                           \
    __builtin_amdgcn_s_barrier();                                                \
    asm volatile("s_waitcnt lgkmcnt(0)" ::: "memory");                           \
    __builtin_amdgcn_sched_barrier(0);                                           \
    __builtin_amdgcn_s_setprio(1);                                               \
    MMQ(ahi, bhi, 4, 2);                                                         \
    __builtin_amdgcn_s_setprio(0);                                               \
    __builtin_amdgcn_sched_barrier(0);                                           \
    __builtin_amdgcn_s_barrier();                                                \
    if (DOSTAGE) {                                                               \
      load_lds16(Ag + (aoff0 + (SKO)), dA0 + (BUF) * 16384);                     \
      load_lds16(Ag + (aoff1 + (SKO)), dA1 + (BUF) * 16384);                     \
      load_lds16(Ag + (aoff2 + (SKO)), dA2 + (BUF) * 16384);                     \
      load_lds16(Ag + (aoff3 + (SKO)), dA3 + (BUF) * 16384);                     \
    }                                                                            \
    __builtin_amdgcn_sched_barrier(0);                                           \
    __builtin_amdgcn_s_barrier();                                                \
    __builtin_amdgcn_s_setprio(1);                                               \
    MMQ(ahi, blo, 4, 0);                                                         \
    __builtin_amdgcn_s_setprio(0);                                               \
    VMSTMT;                                                                      \
    __builtin_amdgcn_sched_barrier(0);                                           \
    __builtin_amdgcn_s_barrier();                                                \
  }

// MODE 0: Cf32[r,col]  = xres[r,col] + (acc+bias[col]) * gate[r]
// MODE 1: Cf32[r,col] += (acc+bias?[col]) * gate?[r]
// MODE 2: fused GLU -> bf16: even col lanes write f2b(a*sigm(b)) at [r, col>>1], stride N/2
// MODE 3: Cb16[r,col] = f2b(aux[r,col] * sigm(acc+bias[col]))
template<int MODE>
__global__ __launch_bounds__(512, 1) void k_gemm(const u16* __restrict__ A, int lda,
    const u16* __restrict__ B, int ldb, void* __restrict__ Cout, int M, int N, int K,
    const float* __restrict__ bias, const float* __restrict__ gate, const u16* __restrict__ aux,
    const float* __restrict__ xres) {
  __shared__ u16 lds[65536];                           // 128 KiB
  int tid = threadIdx.x;
  int w = tid >> 6, lane = tid & 63;
  int l15 = lane & 15, l4 = lane >> 4;
  int wr = w >> 2, wc = w & 3;

  // XCD-aware bijective swizzle, bm-fastest within each XCD's bm band.
  int gx = gridDim.x, gy = gridDim.y;
  int nwg = gx * gy;
  int bid = blockIdx.y * gx + blockIdx.x;
  int bm, bn;
  if (((nwg & 7) == 0) && ((gy & 7) == 0)) {
    int xcd = bid & 7, l = bid >> 3;
    int rpx = gy >> 3;
    bm = xcd * rpx + (l % rpx);
    bn = l / rpx;
  } else { bn = bid % gx; bm = bid / gx; }

  const u16* Ag = A + (size_t)bm * 256 * lda;
  const u16* Bg = B + (size_t)bn * 256 * ldb;
  int nt = K >> 6;

  f32x4 acc[8][4];
#pragma unroll
  for (int m = 0; m < 8; ++m)
#pragma unroll
    for (int n = 0; n < 4; ++n) acc[m][n] = f32x4{0.f, 0.f, 0.f, 0.f};

  int m7 = l15 & 7;
  int slot0 = l4 ^ m7, slot1 = slot0 ^ 4;
  const u16* Ard0 = lds + wr * 8192 + l15 * 64 + slot0 * 8;
  const u16* Ard1 = lds + wr * 8192 + l15 * 64 + slot1 * 8;
  const u16* Brd0 = lds + 32768 + (wc >> 1) * 8192 + ((wc & 1) * 64 + l15) * 64 + slot0 * 8;
  const u16* Brd1 = lds + 32768 + (wc >> 1) * 8192 + ((wc & 1) * 64 + l15) * 64 + slot1 * 8;

  int r0 = tid >> 3;
  int kg = ((lane & 7) ^ (lane >> 3)) * 8;
  int aoff0 = (0 * 128 + 0 * 64 + r0) * lda + kg;
  int aoff1 = (0 * 128 + 1 * 64 + r0) * lda + kg;
  int aoff2 = (1 * 128 + 0 * 64 + r0) * lda + kg;
  int aoff3 = (1 * 128 + 1 * 64 + r0) * lda + kg;
  int boff0 = (0 * 128 + 0 * 64 + r0) * ldb + kg;
  int boff1 = (0 * 128 + 1 * 64 + r0) * ldb + kg;
  int boff2 = (1 * 128 + 0 * 64 + r0) * ldb + kg;
  int boff3 = (1 * 128 + 1 * 64 + r0) * ldb + kg;
  int w512 = w * 512;
  u16* dA0 = lds + 0 * 4096 + w512;
  u16* dA1 = lds + 1 * 4096 + w512;
  u16* dA2 = lds + 2 * 4096 + w512;
  u16* dA3 = lds + 3 * 4096 + w512;
  u16* dB0 = lds + 32768 + 0 * 4096 + w512;
  u16* dB1 = lds + 32768 + 1 * 4096 + w512;
  u16* dB2 = lds + 32768 + 2 * 4096 + w512;
  u16* dB3 = lds + 32768 + 3 * 4096 + w512;

  load_lds16(Bg + boff0, dB0); load_lds16(Bg + boff1, dB1);
  load_lds16(Bg + boff2, dB2); load_lds16(Bg + boff3, dB3);
  load_lds16(Ag + aoff0, dA0); load_lds16(Ag + aoff1, dA1);
  load_lds16(Ag + aoff2, dA2); load_lds16(Ag + aoff3, dA3);
  load_lds16(Bg + boff0 + 64, dB0 + 16384); load_lds16(Bg + boff1 + 64, dB1 + 16384);
  load_lds16(Bg + boff2 + 64, dB2 + 16384); load_lds16(Bg + boff3 + 64, dB3 + 16384);
  load_lds16(Ag + aoff0 + 64, dA0 + 16384); load_lds16(Ag + aoff1 + 64, dA1 + 16384);
  load_lds16(Ag + aoff2 + 64, dA2 + 16384); load_lds16(Ag + aoff3 + 64, dA3 + 16384);
  asm volatile("s_waitcnt vmcnt(8)" ::: "memory");
  __builtin_amdgcn_s_barrier();
  __builtin_amdgcn_sched_barrier(0);

  int koff = 0;
  int main_iters = (nt >> 1) - 1;
  for (int it = 0; it < main_iters; ++it) {
    TILE(0, koff + 128, true, asm volatile("s_waitcnt vmcnt(8)" ::: "memory"));
    TILE(1, koff + 192, true, asm volatile("s_waitcnt vmcnt(8)" ::: "memory"));
    koff += 128;
  }
  TILE(0, 0, false, asm volatile("s_waitcnt vmcnt(0)" ::: "memory"));
  TILE(1, 0, false, (void)0);

  int rowbase = bm * 256 + wr * 128;
  int colbase = bn * 256 + wc * 64;
#pragma unroll
  for (int n = 0; n < 4; ++n) {
    int col = colbase + n * 16 + l15;
    float bv = (MODE == 2) ? 0.f : (bias ? bias[col] : 0.f);
#pragma unroll
    for (int m = 0; m < 8; ++m) {
#pragma unroll
      for (int j = 0; j < 4; ++j) {
        int r = rowbase + m * 16 + l4 * 4 + j;
        float val = acc[m][n][j];
        if (MODE == 0) {
          size_t idx = (size_t)r * N + col;
          ((float*)Cout)[idx] = xres[idx] + (val + bv) * gate[r];
        } else if (MODE == 1) {
          ((float*)Cout)[(size_t)r * N + col] += (val + bv) * (gate ? gate[r] : 1.f);
        } else if (MODE == 2) {
          float other = __shfl_xor(val, 1);
          if ((lane & 1) == 0)
            ((u16*)Cout)[(size_t)r * (N >> 1) + (col >> 1)] = f2b(val * sigm(other));
        } else {
          float a = b2f(aux[(size_t)r * N + col]);
          ((u16*)Cout)[(size_t)r * N + col] = f2b(a * sigm(val + bv));
        }
      }
    }
  }
}

extern "C" void kernel_launch(void* const* d_in, const int* in_sizes, int n_in,
                              void* d_out, int out_size, void* d_ws, size_t ws_size,
                              hipStream_t stream) {
  const float* x        = (const float*)d_in[0];
  const float* norm_w   = (const float*)d_in[1];
  const float* conv_ws  = (const float*)d_in[2];
  const float* conv_bs  = (const float*)d_in[3];
  const float* conv_pw  = (const float*)d_in[4];
  const float* conv_pb  = (const float*)d_in[5];
  const float* gate_w   = (const float*)d_in[6];
  const float* router_w = (const float*)d_in[7];
  const float* router_b = (const float*)d_in[8];
  const float* head_ws  = (const float*)d_in[9];
  const float* head_bs  = (const float*)d_in[10];
  const float* mixg_w   = (const float*)d_in[11];
  const float* mixg_b   = (const float*)d_in[12];
  const float* mix_w    = (const float*)d_in[13];
  const float* mix_b    = (const float*)d_in[14];
  const float* ffn_iw   = (const float*)d_in[15];
  const float* ffn_ow   = (const float*)d_in[16];
  const float* pg_w     = (const float*)d_in[17];
  const float* pg_b     = (const float*)d_in[18];
  float* out = (float*)d_out;

  char* ws = (char*)d_ws;
  size_t o = 0;
  auto alloc = [&](size_t n) { char* p = ws + o; o += n; return p; };
  u16*  XB  = (u16*)alloc(25165824);    // xhat bf16 [8192,1536]
  u16*  A16 = (u16*)alloc(25165824);    // bf16 ping
  u16*  B16 = (u16*)alloc(25165824);    // bf16 pong
  u16*  WG2 = (u16*)alloc(9437184);     // gate_w interleaved * nw1 [3072,1536]
  u16*  WP  = (u16*)alloc(4718592);     // conv_proj [1536,1536]
  u16*  WMG = (u16*)alloc(4718592);     // mix_gate [1536,1536]
  u16*  WMX = (u16*)alloc(4718592);     // mixing [1536,1536]
  u16*  WFI = (u16*)alloc(37748736);    // ffn_in interleaved * nw2 [12288,1536]
  u16*  WFO = (u16*)alloc(18874368);    // ffn_out [1536,6144]
  float* gates = (float*)alloc(98304);  // [3][8192]
  float* hw    = (float*)alloc(393216); // [8192][12]
  u16*  VB = A16;                       // FFN V chunk [8192,3072] bf16 = 50MB (aliases A16+B16)

  k_rmsnorm<<<MT, 256, 0, stream>>>(x, XB);
  k_gates<<<MT, 256, 0, stream>>>(XB, norm_w, pg_w, pg_b, router_w, router_b, gates, hw);

  k_wcvt2<<<dim3(6, 3072),  256, 0, stream>>>(gate_w, WG2, norm_w + H, H, H);
  k_wcvt <<<dim3(6, 1536),  256, 0, stream>>>(conv_pw, WP, nullptr, H);
  k_wcvt <<<dim3(6, 1536),  256, 0, stream>>>(mixg_w, WMG, nullptr, H);
  k_wcvt <<<dim3(6, 1536),  256, 0, stream>>>(mix_w, WMX, nullptr, H);
  k_wcvt2<<<dim3(6, 12288), 256, 0, stream>>>(ffn_iw, WFI, norm_w + 2 * H, H, INNER);
  k_wcvt <<<dim3(24, 1536), 256, 0, stream>>>(ffn_ow, WFO, nullptr, INNER);

  // ---- conv stack path: 6 blocked steps, 4 channels/thread (norm_w0 folded on step 0) ----
  dim3 cg(1, SQ / 8, BB);
  k_conv<<<cg, 384, 0, stream>>>(XB,  A16, conv_ws + 0 * H * 4, conv_bs + 0 * H, 1,  norm_w);
  k_conv<<<cg, 384, 0, stream>>>(A16, B16, conv_ws + 1 * H * 4, conv_bs + 1 * H, 2,  nullptr);
  k_conv<<<cg, 384, 0, stream>>>(B16, A16, conv_ws + 2 * H * 4, conv_bs + 2 * H, 4,  nullptr);
  k_conv<<<cg, 384, 0, stream>>>(A16, B16, conv_ws + 3 * H * 4, conv_bs + 3 * H, 8,  nullptr);
  k_conv<<<cg, 384, 0, stream>>>(B16, A16, conv_ws + 4 * H * 4, conv_bs + 4 * H, 16, nullptr);
  k_conv<<<cg, 384, 0, stream>>>(A16, B16, conv_ws + 5 * H * 4, conv_bs + 5 * H, 32, nullptr);
  // conv_out proj, gated by gc, + residual x fused -> out
  k_gemm<0><<<dim3(6, 32), 512, 0, stream>>>(B16, H, WP, H, out, MT, H, H, conv_pb, gates, nullptr, x);

  // ---- state path ----
  // gate GEMM + fused GLU -> x_gated bf16 in A16
  k_gemm<2><<<dim3(12, 32), 512, 0, stream>>>(XB, H, WG2, H, A16, MT, 2 * H, H, nullptr, nullptr, nullptr, nullptr);
  k_hconv<<<cg, 384, 0, stream>>>(A16, B16, head_ws, head_bs, 0, nullptr);
  k_hconv<<<cg, 384, 0, stream>>>(B16, A16, head_ws, head_bs, 1, nullptr);
  k_hconv<<<cg, 384, 0, stream>>>(A16, B16, head_ws, head_bs, 2, hw);   // j2 + head-weight fused
  // mix_gate GEMM + fused out2: A16 = f2b(B16 * sigm(mg))
  k_gemm<3><<<dim3(6, 32), 512, 0, stream>>>(B16, H, WMG, H, A16, MT, H, H, mixg_b, nullptr, B16, nullptr);
  // mixing GEMM, gated by gs, accumulates into out
  k_gemm<1><<<dim3(6, 32), 512, 0, stream>>>(A16, H, WMX, H, out, MT, H, H, mix_b, gates + MT, nullptr, nullptr);

  // ---- GLU FFN path: chunk ffn_in by N (full M), ffn_out by K (accumulate) ----
  for (int ch = 0; ch < 2; ++ch) {
    k_gemm<2><<<dim3(24, 32), 512, 0, stream>>>(XB, H, WFI + (size_t)ch * 6144 * H, H,
                                                VB, MT, 6144, H, nullptr, nullptr, nullptr, nullptr);
    k_gemm<1><<<dim3(6, 32), 512, 0, stream>>>(VB, 3072, WFO + ch * 3072, INNER,
                                               out, MT, H, 3072, nullptr, gates + 2 * MT, nullptr, nullptr);
  }
}